// Round 4
// baseline (117.655 us; speedup 1.0000x reference)
//
#include <hip/hip_runtime.h>

// MPCM: multi-scale patch contrast measure + per-image mean+3*std threshold.
// f64 interior math (binary output => threshold flips are fatal).
// v4: 64-wide tiles (64x16) so all LDS accesses are row-contiguous per
//     half-wave -> bank-conflict-free; input staged directly as f64 integral
//     buffer (no f32 staging array); 3 blocks/CU retained (53.6 KB LDS).

namespace {

constexpr int H = 512, W = 512, NIMG = 16;
constexpr int TW = 64, TH = 16;          // output tile
constexpr int HALO = 13;                 // max k + k/2 = 9 + 4
constexpr int IR = TH + 2 * HALO + 1;    // 43 integral rows (row 0 = zeros)
constexpr int IC = TW + 2 * HALO + 1;    // 91 integral cols (col 0 = zeros)
constexpr int WI = IC;                   // I stride (doubles)
constexpr int NT = 256;
constexpr int LS = 82;                   // L stride (doubles, even -> 16B-aligned pairs)

struct Smem {
  union alignas(16) {
    double L[34 * LS];                   // 22304 B (max LH = 34 for K=9)
    double red[8];
  } u;
  double I[IR * WI];                     // 31304 B exclusive 2D prefix
};                                       // 53608 B -> 3 blocks/CU

// One scale: box means from integral (zeroed outside image) -> pcm -> max into mp[4].
// pcm mapping: j in {0,1}: row r=(tid>>5)+8j, cols cc..cc+1 with cc=2*(tid&31).
template <int K>
__device__ __forceinline__ void scale_pass(Smem& s, int y0, int x0, double mp[4]) {
  constexpr int R   = K / 2;
  constexpr int LH  = TH + 2 * K;        // L rows
  constexpr int LW  = TW + 2 * K;        // L cols (even)
  constexpr int HPW = LW / 2;            // pairs per L row
  constexpr int NP  = LH * HPW;
  constexpr double inv = 1.0 / (double)(K * K);
  const int tid = threadIdx.x;

  // Box sums via 4 integral corners, two consecutive-x outputs per iteration.
  for (int pe = tid; pe < NP; pe += NT) {
    const int yy = pe / HPW;
    const int xx = (pe - yy * HPW) * 2;
    const int li = yy + (HALO - K);                  // local input row of center
    const int lj = xx + (HALO - K) - R;              // left corner col
    const double* Ia = s.I + (li - R) * WI + lj;     // top corner row
    const double* Ib = Ia + K * WI;                  // bottom+1 corner row
    const double a0 = Ia[0], aK = Ia[K];             // ds_read2_b64 (0,K)
    const double a1 = Ia[1], aK1 = Ia[K + 1];        // ds_read2_b64 (1,K+1)
    const double b0 = Ib[0], bK = Ib[K];
    const double b1 = Ib[1], bK1 = Ib[K + 1];
    const double s0 = (bK  - aK)  - (b0 - a0);
    const double s1 = (bK1 - aK1) - (b1 - a1);
    const int gy = y0 - K + yy, gx = x0 - K + xx;
    const bool in0 = ((unsigned)gy < (unsigned)H) & ((unsigned)gx < (unsigned)W);
    const bool in1 = ((unsigned)gy < (unsigned)H) & ((unsigned)(gx + 1) < (unsigned)W);
    double2 o;
    o.x = in0 ? s0 * inv : 0.0;
    o.y = in1 ? s1 * inv : 0.0;
    *(double2*)&s.u.L[yy * LS + xx] = o;             // 16B aligned (LS even, xx even)
  }
  __syncthreads();

#pragma unroll
  for (int j = 0; j < 2; ++j) {
    const int r  = (tid >> 5) + 8 * j;
    const int cc = (tid & 31) * 2;
    const double* up  = &s.u.L[r * LS + cc];         // L row (r+K) - K
    const double* mid = up + K * LS;
    const double* dn  = up + 2 * K * LS;
    const double2 u0p = *(const double2*)up;                 // b128
    const double  uK = up[K], uK1 = up[K + 1];               // read2
    const double2 u2p = *(const double2*)(up + 2 * K);       // b128
    const double2 m0p = *(const double2*)mid;
    const double  mK = mid[K], mK1 = mid[K + 1];
    const double2 m2p = *(const double2*)(mid + 2 * K);
    const double2 w0p = *(const double2*)dn;
    const double  wK = dn[K], wK1 = dn[K + 1];
    const double2 w2p = *(const double2*)(dn + 2 * K);
    {
      const double c = mK;
      const double e0 = c - u0p.x, e1 = c - uK, e2 = c - u2p.x, e3 = c - m0p.x;
      const double e4 = c - m2p.x, e5 = c - w0p.x, e6 = c - wK, e7 = c - w2p.x;
      const double m = fmin(fmin(e0 * e4, e1 * e5), fmin(e2 * e6, e3 * e7));
      mp[2 * j] = fmax(mp[2 * j], m);
    }
    {
      const double c = mK1;
      const double e0 = c - u0p.y, e1 = c - uK1, e2 = c - u2p.y, e3 = c - m0p.y;
      const double e4 = c - m2p.y, e5 = c - w0p.y, e6 = c - wK1, e7 = c - w2p.y;
      const double m = fmin(fmin(e0 * e4, e1 * e5), fmin(e2 * e6, e3 * e7));
      mp[2 * j + 1] = fmax(mp[2 * j + 1], m);
    }
  }
  __syncthreads();
}

__device__ __forceinline__ void compute_tile(Smem& s, const float* __restrict__ img,
                                             int y0, int x0, double mp[4]) {
  const int tid = threadIdx.x;
  // Stage input directly as f64 into I interior (zero halo + zero row0/col0).
  for (int e = tid; e < IR * IC; e += NT) {
    const int iy = e / IC, ix = e - iy * IC;
    const int gy = y0 - HALO + iy - 1, gx = x0 - HALO + ix - 1;
    double v = 0.0;
    if (iy > 0 && ix > 0 && (unsigned)gy < (unsigned)H && (unsigned)gx < (unsigned)W)
      v = (double)img[gy * W + gx];
    s.I[iy * WI + ix] = v;
  }
  __syncthreads();

  // Row prefix in-place (rows 1..42); reads pipeline ahead of the add chain.
  if (tid < IR - 1) {
    double* p = &s.I[(tid + 1) * WI + 1];
    double run = 0.0;
#pragma unroll
    for (int x = 0; x < IC - 1; ++x) { run += p[x]; p[x] = run; }
  }
  __syncthreads();

  // Col prefix in-place (cols 1..90); lanes on consecutive cols -> conflict-free.
  if (tid < IC - 1) {
    double* p = &s.I[WI + (tid + 1)];
    double run = 0.0;
#pragma unroll
    for (int y = 0; y < IR - 1; ++y) { run += *p; *p = run; p += WI; }
  }
  __syncthreads();

  mp[0] = mp[1] = mp[2] = mp[3] = -1.0e300;
  scale_pass<3>(s, y0, x0, mp);
  scale_pass<5>(s, y0, x0, mp);
  scale_pass<7>(s, y0, x0, mp);
  scale_pass<9>(s, y0, x0, mp);
}

// Pass 1: mpcm -> ws cache + per-block (sum, sumsq) via wave shuffles (fixed order)
__global__ __launch_bounds__(NT, 3) void k_stats(const float* __restrict__ in,
                                                 double* __restrict__ partials,
                                                 double* __restrict__ wsmp) {
  __shared__ Smem s;
  const int img = blockIdx.z;
  const int y0 = blockIdx.y * TH, x0 = blockIdx.x * TW;
  double mp[4];
  compute_tile(s, in + (size_t)img * H * W, y0, x0, mp);

  const int tid = threadIdx.x;
  if (wsmp != nullptr) {
#pragma unroll
    for (int j = 0; j < 2; ++j) {
      const int r = (tid >> 5) + 8 * j, cc = (tid & 31) * 2;
      double2 v; v.x = mp[2 * j]; v.y = mp[2 * j + 1];
      *(double2*)&wsmp[(size_t)img * H * W + (size_t)(y0 + r) * W + (x0 + cc)] = v;
    }
  }

  double s1 = (mp[0] + mp[1]) + (mp[2] + mp[3]);
  double s2 = (mp[0] * mp[0] + mp[1] * mp[1]) + (mp[2] * mp[2] + mp[3] * mp[3]);
#pragma unroll
  for (int off = 32; off; off >>= 1) {
    s1 += __shfl_down(s1, off);
    s2 += __shfl_down(s2, off);
  }
  if ((tid & 63) == 0) { s.u.red[tid >> 6] = s1; s.u.red[4 + (tid >> 6)] = s2; }
  __syncthreads();
  if (tid == 0) {
    const int bl = (img * gridDim.y + blockIdx.y) * gridDim.x + blockIdx.x;
    partials[2 * bl]     = (s.u.red[0] + s.u.red[1]) + (s.u.red[2] + s.u.red[3]);
    partials[2 * bl + 1] = (s.u.red[4] + s.u.red[5]) + (s.u.red[6] + s.u.red[7]);
  }
}

// Pass 2: per-image sequential (deterministic) reduction -> th = mean + 3*std(ddof=1)
__global__ void k_thresh(const double* __restrict__ partials, double* __restrict__ th) {
  const int img = threadIdx.x;
  if (img < NIMG) {
    double S = 0.0, S2 = 0.0;
    const int nb = (H / TH) * (W / TW);
    for (int b = 0; b < nb; ++b) {
      S  += partials[2 * (img * nb + b)];
      S2 += partials[2 * (img * nb + b) + 1];
    }
    const double N = (double)(H * W);
    const double mean = S / N;
    double var = (S2 - S * S / N) / (N - 1.0);
    if (var < 0.0) var = 0.0;
    th[img] = mean + 3.0 * sqrt(var);
  }
}

// Pass 3a (fast): compare cached mpcm against threshold (memory-bound, vectorized)
__global__ __launch_bounds__(NT) void k_out_cached(const double* __restrict__ wsmp,
                                                   const double* __restrict__ th,
                                                   float* __restrict__ out) {
  const int n = NIMG * H * W / 2;
  for (int i = blockIdx.x * NT + threadIdx.x; i < n; i += gridDim.x * NT) {
    const double t = th[i >> 17];  // 2 px per i; H*W/2 = 2^17
    const double2 v = ((const double2*)wsmp)[i];
    float2 o; o.x = (v.x > t) ? 1.0f : 0.0f; o.y = (v.y > t) ? 1.0f : 0.0f;
    ((float2*)out)[i] = o;
  }
}

// Pass 3b (fallback): recompute identical mpcm, write binary output
__global__ __launch_bounds__(NT, 3) void k_out_full(const float* __restrict__ in,
                                                    const double* __restrict__ th,
                                                    float* __restrict__ out) {
  __shared__ Smem s;
  const int img = blockIdx.z;
  const int y0 = blockIdx.y * TH, x0 = blockIdx.x * TW;
  double mp[4];
  compute_tile(s, in + (size_t)img * H * W, y0, x0, mp);
  const double t = th[img];
  const int tid = threadIdx.x;
#pragma unroll
  for (int j = 0; j < 2; ++j) {
    const int r = (tid >> 5) + 8 * j, cc = (tid & 31) * 2;
    float2 o;
    o.x = (mp[2 * j]     > t) ? 1.0f : 0.0f;
    o.y = (mp[2 * j + 1] > t) ? 1.0f : 0.0f;
    *(float2*)&out[(size_t)img * H * W + (size_t)(y0 + r) * W + (x0 + cc)] = o;
  }
}

}  // namespace

extern "C" void kernel_launch(void* const* d_in, const int* in_sizes, int n_in,
                              void* d_out, int out_size, void* d_ws, size_t ws_size,
                              hipStream_t stream) {
  const float* in = (const float*)d_in[0];
  float* out = (float*)d_out;

  // ws layout: [0,128)                th (16 doubles)
  //            [4096, 4096+65536)     partials (4096 blocks x {sum,sumsq})
  //            [131072, +33554432)    mpcm cache (optional)
  double* th = (double*)d_ws;
  double* partials = (double*)((char*)d_ws + 4096);
  double* wsmp = (double*)((char*)d_ws + 131072);
  const bool cache = ws_size >= (size_t)131072 + (size_t)NIMG * H * W * 8;

  dim3 grid(W / TW, H / TH, NIMG);  // (8, 32, 16)
  k_stats<<<grid, NT, 0, stream>>>(in, partials, cache ? wsmp : nullptr);
  k_thresh<<<1, 64, 0, stream>>>(partials, th);
  if (cache) {
    k_out_cached<<<2048, NT, 0, stream>>>(wsmp, th, out);
  } else {
    k_out_full<<<grid, NT, 0, stream>>>(in, th, out);
  }
}

// Round 5
// 93.749 us; speedup vs baseline: 1.2550x; 1.2550x over previous
//
#include <hip/hip_runtime.h>

// MPCM: multi-scale patch contrast measure + per-image mean+3*std threshold.
// f64 interior math (binary output => threshold flips are fatal).
// v5: 64x32 tiles / 512 threads (halo amortization, 16 waves/CU, 75.8KB LDS);
//     all paired LDS loads forced contiguous-per-lane (ld2 -> adjacent-offset
//     ds_read2_b64, conflict-free); interior tiles skip bounds predication.

namespace {

constexpr int H = 512, W = 512, NIMG = 16;
constexpr int TW = 64, TH = 32;          // output tile
constexpr int HALO = 13;                 // max k + k/2 = 9 + 4
constexpr int IR = TH + 2 * HALO + 1;    // 59 integral rows (row 0 = zeros)
constexpr int IC = TW + 2 * HALO + 1;    // 91 integral cols (col 0 = zeros)
constexpr int WI = IC;                   // I stride (doubles, odd -> good prefix banking)
constexpr int NT = 512;
constexpr int LS = 82;                   // L stride (doubles, even -> aligned pairs)

struct Smem {
  union alignas(16) {
    double L[(TH + 18) * LS];            // 50*82*8 = 32800 B (max LH for K=9)
    double red[16];
  } u;
  double I[IR * WI];                     // 59*91*8 = 42952 B exclusive 2D prefix
};                                       // 75752 B -> 2 blocks/CU (gfx950: 160KB LDS)

// Contiguous-per-lane 16B LDS load (align 8) -> adjacent-offset ds_read2_b64 / b128.
__device__ __forceinline__ double2 ld2(const double* p) {
  double2 v;
  __builtin_memcpy(&v, p, sizeof(double2));
  return v;
}

// One scale: box means from integral (zeroed outside image) -> pcm -> max into mp[4].
// pcm mapping: j in {0,1}: row r=(tid>>5)+16j, cols cc..cc+1 with cc=2*(tid&31).
template <int K, bool BORDER>
__device__ __forceinline__ void scale_pass(Smem& s, int y0, int x0, double mp[4]) {
  constexpr int R   = K / 2;
  constexpr int LH  = TH + 2 * K;        // L rows
  constexpr int LW  = TW + 2 * K;        // L cols (even)
  constexpr int HPW = LW / 2;            // pairs per L row
  constexpr int NP  = LH * HPW;
  constexpr double inv = 1.0 / (double)(K * K);
  const int tid = threadIdx.x;

  // Box sums via 4 integral corners; 2 consecutive-x outputs per iteration.
  // Corner loads are contiguous 16B per lane -> conflict-free.
  for (int pe = tid; pe < NP; pe += NT) {
    const int yy = pe / HPW;
    const int xx = (pe - yy * HPW) * 2;
    const int li = yy + (HALO - K);                  // local input row of center
    const int lj = xx + (HALO - K) - R;              // left corner col
    const double* Ia = s.I + (li - R) * WI + lj;     // top corner row
    const double* Ib = Ia + K * WI;                  // bottom+1 corner row
    const double2 a0 = ld2(Ia), aK = ld2(Ia + K);
    const double2 b0 = ld2(Ib), bK = ld2(Ib + K);
    const double s0 = (bK.x - aK.x) - (b0.x - a0.x);
    const double s1 = (bK.y - aK.y) - (b0.y - a0.y);
    double2 o;
    if (BORDER) {
      const int gy = y0 - K + yy, gx = x0 - K + xx;
      const bool in0 = ((unsigned)gy < (unsigned)H) & ((unsigned)gx < (unsigned)W);
      const bool in1 = ((unsigned)gy < (unsigned)H) & ((unsigned)(gx + 1) < (unsigned)W);
      o.x = in0 ? s0 * inv : 0.0;
      o.y = in1 ? s1 * inv : 0.0;
    } else {
      o.x = s0 * inv;
      o.y = s1 * inv;
    }
    *(double2*)&s.u.L[yy * LS + xx] = o;             // 16B aligned (LS even, xx even)
  }
  __syncthreads();

#pragma unroll
  for (int j = 0; j < 2; ++j) {
    const int r  = (tid >> 5) + 16 * j;
    const int cc = (tid & 31) * 2;
    const double* up  = &s.u.L[r * LS + cc];         // L row (r+K) - K
    const double* mid = up + K * LS;
    const double* dn  = up + 2 * K * LS;
    const double2 u0 = ld2(up),  uK = ld2(up + K),  u2 = ld2(up + 2 * K);
    const double2 m0 = ld2(mid), mK = ld2(mid + K), m2 = ld2(mid + 2 * K);
    const double2 w0 = ld2(dn),  wK = ld2(dn + K),  w2 = ld2(dn + 2 * K);
    {
      const double c = mK.x;
      const double e0 = c - u0.x, e1 = c - uK.x, e2 = c - u2.x, e3 = c - m0.x;
      const double e4 = c - m2.x, e5 = c - w0.x, e6 = c - wK.x, e7 = c - w2.x;
      const double m = fmin(fmin(e0 * e4, e1 * e5), fmin(e2 * e6, e3 * e7));
      mp[2 * j] = fmax(mp[2 * j], m);
    }
    {
      const double c = mK.y;
      const double e0 = c - u0.y, e1 = c - uK.y, e2 = c - u2.y, e3 = c - m0.y;
      const double e4 = c - m2.y, e5 = c - w0.y, e6 = c - wK.y, e7 = c - w2.y;
      const double m = fmin(fmin(e0 * e4, e1 * e5), fmin(e2 * e6, e3 * e7));
      mp[2 * j + 1] = fmax(mp[2 * j + 1], m);
    }
  }
  __syncthreads();
}

template <bool BORDER>
__device__ __forceinline__ void compute_tile(Smem& s, const float* __restrict__ img,
                                             int y0, int x0, double mp[4]) {
  const int tid = threadIdx.x;
  // Stage input directly as f64 into I interior (zero halo + zero row0/col0).
  for (int e = tid; e < IR * IC; e += NT) {
    const int iy = e / IC, ix = e - iy * IC;
    const int gy = y0 - HALO + iy - 1, gx = x0 - HALO + ix - 1;
    double v = 0.0;
    if (BORDER) {
      if (iy > 0 && ix > 0 && (unsigned)gy < (unsigned)H && (unsigned)gx < (unsigned)W)
        v = (double)img[gy * W + gx];
    } else {
      if (iy > 0 && ix > 0) v = (double)img[gy * W + gx];
    }
    s.I[iy * WI + ix] = v;
  }
  __syncthreads();

  // Row prefix in-place (rows 1..IR-1).
  if (tid < IR - 1) {
    double* p = &s.I[(tid + 1) * WI + 1];
    double run = 0.0;
#pragma unroll
    for (int x = 0; x < IC - 1; ++x) { run += p[x]; p[x] = run; }
  }
  __syncthreads();

  // Col prefix in-place (cols 1..IC-1); lanes on consecutive cols -> conflict-free.
  if (tid < IC - 1) {
    double* p = &s.I[WI + (tid + 1)];
    double run = 0.0;
#pragma unroll
    for (int y = 0; y < IR - 1; ++y) { run += *p; *p = run; p += WI; }
  }
  __syncthreads();

  mp[0] = mp[1] = mp[2] = mp[3] = -1.0e300;
  scale_pass<3, BORDER>(s, y0, x0, mp);
  scale_pass<5, BORDER>(s, y0, x0, mp);
  scale_pass<7, BORDER>(s, y0, x0, mp);
  scale_pass<9, BORDER>(s, y0, x0, mp);
}

// Pass 1: mpcm -> ws cache + per-block (sum, sumsq) via wave shuffles (fixed order)
__global__ __launch_bounds__(NT, 4) void k_stats(const float* __restrict__ in,
                                                 double* __restrict__ partials,
                                                 double* __restrict__ wsmp) {
  __shared__ Smem s;
  const int img = blockIdx.z;
  const int y0 = blockIdx.y * TH, x0 = blockIdx.x * TW;
  const bool border = (blockIdx.x == 0) | (blockIdx.x == gridDim.x - 1) |
                      (blockIdx.y == 0) | (blockIdx.y == gridDim.y - 1);
  double mp[4];
  if (border) compute_tile<true>(s, in + (size_t)img * H * W, y0, x0, mp);
  else        compute_tile<false>(s, in + (size_t)img * H * W, y0, x0, mp);

  const int tid = threadIdx.x;
  if (wsmp != nullptr) {
#pragma unroll
    for (int j = 0; j < 2; ++j) {
      const int r = (tid >> 5) + 16 * j, cc = (tid & 31) * 2;
      double2 v; v.x = mp[2 * j]; v.y = mp[2 * j + 1];
      *(double2*)&wsmp[(size_t)img * H * W + (size_t)(y0 + r) * W + (x0 + cc)] = v;
    }
  }

  double s1 = (mp[0] + mp[1]) + (mp[2] + mp[3]);
  double s2 = (mp[0] * mp[0] + mp[1] * mp[1]) + (mp[2] * mp[2] + mp[3] * mp[3]);
#pragma unroll
  for (int off = 32; off; off >>= 1) {
    s1 += __shfl_down(s1, off);
    s2 += __shfl_down(s2, off);
  }
  if ((tid & 63) == 0) { s.u.red[tid >> 6] = s1; s.u.red[8 + (tid >> 6)] = s2; }
  __syncthreads();
  if (tid == 0) {
    double S = 0.0, S2 = 0.0;
#pragma unroll
    for (int w = 0; w < NT / 64; ++w) { S += s.u.red[w]; S2 += s.u.red[8 + w]; }
    const int bl = (img * gridDim.y + blockIdx.y) * gridDim.x + blockIdx.x;
    partials[2 * bl]     = S;
    partials[2 * bl + 1] = S2;
  }
}

// Pass 2: per-image sequential (deterministic) reduction -> th = mean + 3*std(ddof=1)
__global__ void k_thresh(const double* __restrict__ partials, double* __restrict__ th) {
  const int img = threadIdx.x;
  if (img < NIMG) {
    double S = 0.0, S2 = 0.0;
    const int nb = (H / TH) * (W / TW);
    for (int b = 0; b < nb; ++b) {
      S  += partials[2 * (img * nb + b)];
      S2 += partials[2 * (img * nb + b) + 1];
    }
    const double N = (double)(H * W);
    const double mean = S / N;
    double var = (S2 - S * S / N) / (N - 1.0);
    if (var < 0.0) var = 0.0;
    th[img] = mean + 3.0 * sqrt(var);
  }
}

// Pass 3a (fast): compare cached mpcm against threshold (memory-bound, vectorized)
__global__ __launch_bounds__(256) void k_out_cached(const double* __restrict__ wsmp,
                                                    const double* __restrict__ th,
                                                    float* __restrict__ out) {
  const int n = NIMG * H * W / 2;
  for (int i = blockIdx.x * 256 + threadIdx.x; i < n; i += gridDim.x * 256) {
    const double t = th[i >> 17];  // 2 px per i; H*W/2 = 2^17
    const double2 v = ((const double2*)wsmp)[i];
    float2 o; o.x = (v.x > t) ? 1.0f : 0.0f; o.y = (v.y > t) ? 1.0f : 0.0f;
    ((float2*)out)[i] = o;
  }
}

// Pass 3b (fallback): recompute identical mpcm, write binary output
__global__ __launch_bounds__(NT, 4) void k_out_full(const float* __restrict__ in,
                                                    const double* __restrict__ th,
                                                    float* __restrict__ out) {
  __shared__ Smem s;
  const int img = blockIdx.z;
  const int y0 = blockIdx.y * TH, x0 = blockIdx.x * TW;
  const bool border = (blockIdx.x == 0) | (blockIdx.x == gridDim.x - 1) |
                      (blockIdx.y == 0) | (blockIdx.y == gridDim.y - 1);
  double mp[4];
  if (border) compute_tile<true>(s, in + (size_t)img * H * W, y0, x0, mp);
  else        compute_tile<false>(s, in + (size_t)img * H * W, y0, x0, mp);
  const double t = th[img];
  const int tid = threadIdx.x;
#pragma unroll
  for (int j = 0; j < 2; ++j) {
    const int r = (tid >> 5) + 16 * j, cc = (tid & 31) * 2;
    float2 o;
    o.x = (mp[2 * j]     > t) ? 1.0f : 0.0f;
    o.y = (mp[2 * j + 1] > t) ? 1.0f : 0.0f;
    *(float2*)&out[(size_t)img * H * W + (size_t)(y0 + r) * W + (x0 + cc)] = o;
  }
}

}  // namespace

extern "C" void kernel_launch(void* const* d_in, const int* in_sizes, int n_in,
                              void* d_out, int out_size, void* d_ws, size_t ws_size,
                              hipStream_t stream) {
  const float* in = (const float*)d_in[0];
  float* out = (float*)d_out;

  // ws layout: [0,128)                th (16 doubles)
  //            [4096, 4096+32768)     partials (2048 blocks x {sum,sumsq})
  //            [131072, +33554432)    mpcm cache (optional)
  double* th = (double*)d_ws;
  double* partials = (double*)((char*)d_ws + 4096);
  double* wsmp = (double*)((char*)d_ws + 131072);
  const bool cache = ws_size >= (size_t)131072 + (size_t)NIMG * H * W * 8;

  dim3 grid(W / TW, H / TH, NIMG);  // (8, 16, 16)
  k_stats<<<grid, NT, 0, stream>>>(in, partials, cache ? wsmp : nullptr);
  k_thresh<<<1, 64, 0, stream>>>(partials, th);
  if (cache) {
    k_out_cached<<<2048, 256, 0, stream>>>(wsmp, th, out);
  } else {
    k_out_full<<<grid, NT, 0, stream>>>(in, th, out);
  }
}